// Round 1
// baseline (141.832 us; speedup 1.0000x reference)
//
#include <hip/hip_runtime.h>
#include <hip/hip_bf16.h>

#define B_ 16
#define T_ 1024
#define C_ 1024
#define T2_ (T_ + 2)
#define PAD_IDX_ 1
#define EPS_ 1e-5f

// Reduce (sum, sumsq) across a 256-thread block. 4 waves of 64.
__device__ __forceinline__ float2 block_reduce_pair(float s, float q, float* smem) {
    #pragma unroll
    for (int off = 32; off > 0; off >>= 1) {
        s += __shfl_down(s, off, 64);
        q += __shfl_down(q, off, 64);
    }
    const int lane = threadIdx.x & 63;
    const int wave = threadIdx.x >> 6;
    if (lane == 0) { smem[wave] = s; smem[4 + wave] = q; }
    __syncthreads();
    s = smem[0] + smem[1] + smem[2] + smem[3];
    q = smem[4] + smem[5] + smem[6] + smem[7];
    return make_float2(s, q);
}

// Kernel A: LN of bos (block 0) and eos (block 1) with ln_s params -> ws[0..C), ws[C..2C)
__global__ __launch_bounds__(256) void special_ln_kernel(
        const float* __restrict__ bos, const float* __restrict__ eos,
        const float* __restrict__ g, const float* __restrict__ be,
        float* __restrict__ ws) {
    __shared__ float smem[8];
    const float* src = (blockIdx.x == 0) ? bos : eos;
    float* dst = ws + (size_t)blockIdx.x * C_;
    const int i = threadIdx.x * 4;
    float4 v = *(const float4*)(src + i);
    float s = v.x + v.y + v.z + v.w;
    float q = v.x * v.x + v.y * v.y + v.z * v.z + v.w * v.w;
    float2 r = block_reduce_pair(s, q, smem);
    const float inv_c = 1.0f / C_;
    float mu = r.x * inv_c;
    float var = r.y * inv_c - mu * mu;
    float rs = rsqrtf(var + EPS_);
    float4 gv = *(const float4*)(g + i);
    float4 bv = *(const float4*)(be + i);
    float4 o;
    o.x = (v.x - mu) * rs * gv.x + bv.x;
    o.y = (v.y - mu) * rs * gv.y + bv.y;
    o.z = (v.z - mu) * rs * gv.z + bv.z;
    o.w = (v.w - mu) * rs * gv.w + bv.w;
    *(float4*)(dst + i) = o;
}

// Kernel B: one block per output row (b, t) of (B, T+2, C).
__global__ __launch_bounds__(256) void row_kernel(
        const float* __restrict__ x, const int* __restrict__ lengths,
        const float* __restrict__ pos_table, const float* __restrict__ scale,
        const float* __restrict__ g, const float* __restrict__ be,
        const float* __restrict__ ws,
        float* __restrict__ out, float* __restrict__ pad_out,
        float* __restrict__ l2_out) {
    __shared__ float smem[8];
    const int row = blockIdx.x;
    const int b = row / T2_;
    const int t = row - b * T2_;
    const int len = lengths[b];
    const int l1 = len + 1;
    const int l2 = len + 2;
    const int i = threadIdx.x * 4;

    float4 v;
    if (t == 0) {
        v = *(const float4*)(ws + i);                      // LN(bos)
    } else if (t == l1) {
        v = *(const float4*)(ws + C_ + i);                 // LN(eos)
    } else if (t <= len) {
        v = *(const float4*)(x + ((size_t)b * T_ + (t - 1)) * (size_t)C_ + i);
    } else {
        v = make_float4(0.f, 0.f, 0.f, 0.f);
    }

    const int pos = (t < l2) ? (t + 2) : PAD_IDX_;
    float4 pe = *(const float4*)(pos_table + (size_t)pos * C_ + i);
    const float sc = scale[0];

    float4 y;
    y.x = v.x * sc + pe.x;
    y.y = v.y * sc + pe.y;
    y.z = v.z * sc + pe.z;
    y.w = v.w * sc + pe.w;

    float s = y.x + y.y + y.z + y.w;
    float q = y.x * y.x + y.y * y.y + y.z * y.z + y.w * y.w;
    float2 r = block_reduce_pair(s, q, smem);
    const float inv_c = 1.0f / C_;
    float mu = r.x * inv_c;
    float var = r.y * inv_c - mu * mu;
    float rs = rsqrtf(var + EPS_);

    float4 gv = *(const float4*)(g + i);
    float4 bv = *(const float4*)(be + i);
    float4 o;
    o.x = (y.x - mu) * rs * gv.x + bv.x;
    o.y = (y.y - mu) * rs * gv.y + bv.y;
    o.z = (y.z - mu) * rs * gv.z + bv.z;
    o.w = (y.w - mu) * rs * gv.w + bv.w;
    *(float4*)(out + (size_t)row * C_ + i) = o;

    if (threadIdx.x == 0) {
        pad_out[row] = (t >= l2) ? 1.0f : 0.0f;
        if (t == 0) l2_out[b] = (float)l2;
    }
}

extern "C" void kernel_launch(void* const* d_in, const int* in_sizes, int n_in,
                              void* d_out, int out_size, void* d_ws, size_t ws_size,
                              hipStream_t stream) {
    const float* x         = (const float*)d_in[0];
    const int*   lengths   = (const int*)d_in[1];
    const float* bos_emb   = (const float*)d_in[2];
    const float* eos_emb   = (const float*)d_in[3];
    const float* ln_s_g    = (const float*)d_in[4];
    const float* ln_s_b    = (const float*)d_in[5];
    const float* pos_table = (const float*)d_in[6];
    const float* scale     = (const float*)d_in[7];
    const float* ln_e_g    = (const float*)d_in[8];
    const float* ln_e_b    = (const float*)d_in[9];

    float* out = (float*)d_out;
    float* pad_out = out + (size_t)B_ * T2_ * C_;
    float* l2_out  = pad_out + (size_t)B_ * T2_;
    float* ws = (float*)d_ws;

    special_ln_kernel<<<2, 256, 0, stream>>>(bos_emb, eos_emb, ln_s_g, ln_s_b, ws);
    row_kernel<<<B_ * T2_, 256, 0, stream>>>(x, lengths, pos_table, scale,
                                             ln_e_g, ln_e_b, ws,
                                             out, pad_out, l2_out);
}

// Round 3
// 140.386 us; speedup vs baseline: 1.0103x; 1.0103x over previous
//
#include <hip/hip_runtime.h>
#include <hip/hip_bf16.h>

#define B_ 16
#define T_ 1024
#define C_ 1024
#define T2_ (T_ + 2)
#define PAD_IDX_ 1
#define EPS_ 1e-5f

typedef float nfloat4 __attribute__((ext_vector_type(4)));

// Reduce (sum, sumsq) across a 256-thread block. 4 waves of 64.
// smem must have 8 floats; callers using it twice pass disjoint regions.
__device__ __forceinline__ float2 block_reduce_pair(float s, float q, float* smem) {
    #pragma unroll
    for (int off = 32; off > 0; off >>= 1) {
        s += __shfl_down(s, off, 64);
        q += __shfl_down(q, off, 64);
    }
    const int lane = threadIdx.x & 63;
    const int wave = threadIdx.x >> 6;
    if (lane == 0) { smem[wave] = s; smem[4 + wave] = q; }
    __syncthreads();
    s = smem[0] + smem[1] + smem[2] + smem[3];
    q = smem[4] + smem[5] + smem[6] + smem[7];
    return make_float2(s, q);
}

// One block per output row (b, t) of (B, T+2, C). LN_s of bos/eos computed
// inline by the (block-uniform) rows that need it.
__global__ __launch_bounds__(256) void fused_row_kernel(
        const float* __restrict__ x, const int* __restrict__ lengths,
        const float* __restrict__ bos, const float* __restrict__ eos,
        const float* __restrict__ sg, const float* __restrict__ sb,
        const float* __restrict__ pos_table, const float* __restrict__ scale,
        const float* __restrict__ g, const float* __restrict__ be,
        float* __restrict__ out, float* __restrict__ pad_out,
        float* __restrict__ l2_out) {
    __shared__ float smem[16];
    const int row = blockIdx.x;
    const int b = row / T2_;
    const int t = row - b * T2_;
    const int len = lengths[b];
    const int l1 = len + 1;
    const int l2 = len + 2;
    const int i = threadIdx.x * 4;
    const float inv_c = 1.0f / C_;

    nfloat4 v;
    if (t == 0 || t == l1) {
        // block-uniform branch: safe to __syncthreads inside
        const float* src = (t == 0) ? bos : eos;
        nfloat4 e = *(const nfloat4*)(src + i);
        float s = e.x + e.y + e.z + e.w;
        float q = e.x * e.x + e.y * e.y + e.z * e.z + e.w * e.w;
        float2 r = block_reduce_pair(s, q, smem + 8);   // disjoint smem region
        float mu = r.x * inv_c;
        float var = r.y * inv_c - mu * mu;
        float rs = rsqrtf(var + EPS_);
        nfloat4 gv = *(const nfloat4*)(sg + i);
        nfloat4 bv = *(const nfloat4*)(sb + i);
        v = (e - mu) * rs * gv + bv;
    } else if (t <= len) {
        // streaming read, no reuse: nontemporal to spare L2 for pos_table
        const nfloat4* p = (const nfloat4*)(x + ((size_t)b * T_ + (t - 1)) * (size_t)C_ + i);
        v = __builtin_nontemporal_load(p);
    } else {
        v = (nfloat4)(0.f);
    }

    const int pos = (t < l2) ? (t + 2) : PAD_IDX_;
    nfloat4 pe = *(const nfloat4*)(pos_table + (size_t)pos * C_ + i);
    const float sc = scale[0];

    nfloat4 y = v * sc + pe;

    float s = y.x + y.y + y.z + y.w;
    float q = y.x * y.x + y.y * y.y + y.z * y.z + y.w * y.w;
    float2 r = block_reduce_pair(s, q, smem);
    float mu = r.x * inv_c;
    float var = r.y * inv_c - mu * mu;
    float rs = rsqrtf(var + EPS_);

    nfloat4 gv = *(const nfloat4*)(g + i);
    nfloat4 bv = *(const nfloat4*)(be + i);
    nfloat4 o = (y - mu) * rs * gv + bv;
    nfloat4* outp = (nfloat4*)(out + (size_t)row * C_ + i);
    __builtin_nontemporal_store(o, outp);   // streaming write, spare L2

    if (threadIdx.x == 0) {
        pad_out[row] = (t >= l2) ? 1.0f : 0.0f;
        if (t == 0) l2_out[b] = (float)l2;
    }
}

extern "C" void kernel_launch(void* const* d_in, const int* in_sizes, int n_in,
                              void* d_out, int out_size, void* d_ws, size_t ws_size,
                              hipStream_t stream) {
    const float* x         = (const float*)d_in[0];
    const int*   lengths   = (const int*)d_in[1];
    const float* bos_emb   = (const float*)d_in[2];
    const float* eos_emb   = (const float*)d_in[3];
    const float* ln_s_g    = (const float*)d_in[4];
    const float* ln_s_b    = (const float*)d_in[5];
    const float* pos_table = (const float*)d_in[6];
    const float* scale     = (const float*)d_in[7];
    const float* ln_e_g    = (const float*)d_in[8];
    const float* ln_e_b    = (const float*)d_in[9];

    float* out = (float*)d_out;
    float* pad_out = out + (size_t)B_ * T2_ * C_;
    float* l2_out  = pad_out + (size_t)B_ * T2_;

    fused_row_kernel<<<B_ * T2_, 256, 0, stream>>>(
        x, lengths, bos_emb, eos_emb, ln_s_g, ln_s_b, pos_table, scale,
        ln_e_g, ln_e_b, out, pad_out, l2_out);
}